// Round 7
// baseline (3624.313 us; speedup 1.0000x reference)
//
#include <hip/hip_runtime.h>
#include <hip/hip_fp16.h>

typedef _Float16 half8 __attribute__((ext_vector_type(8)));
typedef float floatx4 __attribute__((ext_vector_type(4)));
typedef unsigned int u32x4 __attribute__((ext_vector_type(4)));

// B=128, T=512, E=256, H=512, OUT=9, L=2. Quirk: both layers use Uk_w[0]/Uk_b[0].
//
// zfrag layout (verified): 16B granules [t][bt][c16][b15]; granule g = c16*16+b15
// holds z[b = bt*16 + b15][h = c16*8 .. +8). Consumer lane (m,q) A-frag for
// K-block kk is granule (kk*4+q)*16 + m. Tile = 1024 granules = 16 KB.
//
// ENCODED STORAGE: z stored as enc = z + 2 (f16 in [1,3], bits 0x3C00..0x4200).
// Poison 0xAA and zeros fall outside -> an 8B word is valid iff its low f16 is
// in range. Each z address transitions poison->final exactly ONCE, so any
// stale/torn read returns poison (invalid), never valid-but-wrong.
//
// R7 change: 2-BLOCK SPLIT + SELF-HALF FROM LDS (volume attack, per R3-R6
// evidence that step time tracks poll/publish op volume at the coherence pt).
//  - 32 blocks x 512 thr (8 waves, 2/SIMD). Block = (layer, ct in {0,1}, bt);
//    owns cols [ct*256, +256). blk&7 = bt -> communicating set same XCD.
//  - A thread's own stored granule is 512*ct + tid == its j==ct staging slot:
//    own half of every tile comes from registers/LDS (pv carried), NEVER
//    polled -> each thread polls ONE 16B word/step; own-store-drain RT leaves
//    the chain. Per-(bt,step) poll volume 160->64 KB.

union H8 { half8 v; unsigned long long u[2]; };

__device__ __forceinline__ bool valid16(unsigned long long u) {
  return (unsigned)((unsigned)(u & 0xFFFFull) - 0x3C00u) <= 0x600u;  // f16 in [1.0, 3.0]
}

__device__ __forceinline__ unsigned val16B(u32x4 r, unsigned long long g[2]) {
  unsigned long long lo = ((unsigned long long)r[1] << 32) | r[0];
  unsigned long long hi = ((unsigned long long)r[3] << 32) | r[2];
  unsigned need = 0;
  if (valid16(lo)) g[0] = lo; else need |= 1u;
  if (valid16(hi)) g[1] = hi; else need |= 2u;
  return need;
}

__device__ __forceinline__ void retry16B(const char* addr, unsigned long long g[2],
                                         unsigned need, int sleep) {
  while (need) {
    if (sleep) __builtin_amdgcn_s_sleep(1);
    u32x4 r;
    asm volatile("global_load_dwordx4 %0, %1, off sc0 sc1" : "=&v"(r) : "v"(addr) : "memory");
    asm volatile("s_waitcnt vmcnt(0)" ::: "memory");
    __builtin_amdgcn_sched_barrier(0);
    unsigned long long lo = ((unsigned long long)r[1] << 32) | r[0];
    unsigned long long hi = ((unsigned long long)r[3] << 32) | r[2];
    if ((need & 1u) && valid16(lo)) { g[0] = lo; need &= ~1u; }
    if ((need & 2u) && valid16(hi)) { g[1] = hi; need &= ~2u; }
  }
}

// stage one full 16KB z tile into LDS, 512 threads, 2 words/thread (for azs)
__device__ __forceinline__ void stage_azs(const _Float16* srcTile, _Float16* dst, int tid) {
  const char* b0 = (const char*)srcTile + (size_t)tid * 16;
  const char* b1 = (const char*)srcTile + (size_t)(tid + 512) * 16;
  u32x4 r0, r1;
  asm volatile("global_load_dwordx4 %0, %1, off sc0 sc1" : "=&v"(r0) : "v"(b0) : "memory");
  asm volatile("global_load_dwordx4 %0, %1, off sc0 sc1" : "=&v"(r1) : "v"(b1) : "memory");
  asm volatile("s_waitcnt vmcnt(0)" ::: "memory");
  __builtin_amdgcn_sched_barrier(0);
  unsigned long long g0[2], g1[2];
  unsigned n0 = val16B(r0, g0), n1 = val16B(r1, g1);
  while (n0 | n1) {
    __builtin_amdgcn_s_sleep(1);
    u32x4 s0, s1;
    if (n0) asm volatile("global_load_dwordx4 %0, %1, off sc0 sc1" : "=&v"(s0) : "v"(b0) : "memory");
    if (n1) asm volatile("global_load_dwordx4 %0, %1, off sc0 sc1" : "=&v"(s1) : "v"(b1) : "memory");
    asm volatile("s_waitcnt vmcnt(0)" ::: "memory");
    __builtin_amdgcn_sched_barrier(0);
    if (n0) {
      unsigned long long lo = ((unsigned long long)s0[1] << 32) | s0[0];
      unsigned long long hi = ((unsigned long long)s0[3] << 32) | s0[2];
      if ((n0 & 1u) && valid16(lo)) { g0[0] = lo; n0 &= ~1u; }
      if ((n0 & 2u) && valid16(hi)) { g0[1] = hi; n0 &= ~2u; }
    }
    if (n1) {
      unsigned long long lo = ((unsigned long long)s1[1] << 32) | s1[0];
      unsigned long long hi = ((unsigned long long)s1[3] << 32) | s1[2];
      if ((n1 & 1u) && valid16(lo)) { g1[0] = lo; n1 &= ~1u; }
      if ((n1 & 2u) && valid16(hi)) { g1[1] = hi; n1 &= ~2u; }
    }
  }
  H8 t0; t0.u[0] = g0[0]; t0.u[1] = g0[1];
  *(half8*)&dst[(size_t)tid * 8] = t0.v;
  H8 t1; t1.u[0] = g1[0]; t1.u[1] = g1[1];
  *(half8*)&dst[(size_t)(tid + 512) * 8] = t1.v;
}

// ---------------- prep: V pad, fused biases, f16-rounded weight row-sums ----------------
__global__ void prep_small(const float* __restrict__ Vw, const float* __restrict__ Vb,
                           const float* __restrict__ Wb, const float* __restrict__ Ukb,
                           const float* __restrict__ Wkb, const float* __restrict__ Ukw,
                           const float* __restrict__ Wkw, _Float16* __restrict__ V16,
                           float* __restrict__ bxp, float* __restrict__ bc,
                           float* __restrict__ sums) {
  int i = blockIdx.x * blockDim.x + threadIdx.x;
  if (i < 16 * 512) {
    int o = i >> 9, k = i & 511;
    V16[i] = (_Float16)(o < 9 ? Vw[o * 512 + k] : 0.0f);
  }
  if (i < 512) {
    bxp[i] = Wb[i] + Ukb[i];   // layer-0 pre-activation bias (folded into xp)
    bc[i]  = Wkb[i] + Ukb[i];  // layer-1 pre-activation bias
  }
  if (i < 1024) {  // sums[0..511]=rowsum f16(U); [512..1023]=rowsum f16(Wk)
    const float* row = (i < 512) ? Ukw + (size_t)i * 512 : Wkw + (size_t)(i - 512) * 512;
    float s = 0.f;
    for (int k = 0; k < 512; k += 4) {
      float4 v = *(const float4*)(row + k);
      s += (float)(_Float16)v.x + (float)(_Float16)v.y + (float)(_Float16)v.z + (float)(_Float16)v.w;
    }
    sums[i] = s;
  } else if (i < 1040) {  // sums[1024..1039] = out bias: Vb - 2*rowsum f16(V)
    int o = i - 1024;
    float s = 0.f;
    if (o < 9) {
      const float* row = Vw + (size_t)o * 512;
      for (int k = 0; k < 512; k += 4) {
        float4 v = *(const float4*)(row + k);
        s += (float)(_Float16)v.x + (float)(_Float16)v.y + (float)(_Float16)v.z + (float)(_Float16)v.w;
      }
    }
    sums[i] = (o < 9 ? Vb[o] : 0.f) - 2.f * s;
  }
}

// ---------------- xp GEMM: xp[t][b][:] = emb[b][t][:] @ W^T + (Wb+Ukb0), f32 in, f16 out ----
__global__ __launch_bounds__(256) void gemm_xp(const float* __restrict__ Aptr,
                                               const float* __restrict__ Bptr,
                                               _Float16* __restrict__ Cout,
                                               const float* __restrict__ bias) {
  const int K = 256;
  __shared__ __align__(16) _Float16 As[128][40];
  __shared__ __align__(16) _Float16 Bs[128][40];
  const int tid = threadIdx.x;
  const int bm = blockIdx.x, bn = blockIdx.y;
  const int w = tid >> 6, lane = tid & 63;
  const int m = lane & 15, q = lane >> 4;

  floatx4 acc[2][8];
#pragma unroll
  for (int i = 0; i < 2; ++i)
#pragma unroll
    for (int j = 0; j < 8; ++j) acc[i][j] = (floatx4){0.f, 0.f, 0.f, 0.f};

  for (int kt = 0; kt < (K >> 5); ++kt) {
    const int k0 = kt << 5;
    __syncthreads();
#pragma unroll
    for (int it = 0; it < 2; ++it) {
      int idx = tid + it * 256;
      int row = idx >> 2, ch = idx & 3;
      size_t gA = (size_t)(bm * 128 + row) * K + (k0 + ch * 8);
      const float4* p = (const float4*)(Aptr + gA);
      float4 f0 = p[0], f1 = p[1];
      *(half8*)&As[row][ch * 8] =
          (half8){(_Float16)f0.x, (_Float16)f0.y, (_Float16)f0.z, (_Float16)f0.w,
                  (_Float16)f1.x, (_Float16)f1.y, (_Float16)f1.z, (_Float16)f1.w};
      size_t gB = (size_t)(bn * 128 + row) * K + (k0 + ch * 8);
      const float4* pb = (const float4*)(Bptr + gB);
      float4 g0 = pb[0], g1 = pb[1];
      *(half8*)&Bs[row][ch * 8] =
          (half8){(_Float16)g0.x, (_Float16)g0.y, (_Float16)g0.z, (_Float16)g0.w,
                  (_Float16)g1.x, (_Float16)g1.y, (_Float16)g1.z, (_Float16)g1.w};
    }
    __syncthreads();
    half8 a[2], b[8];
#pragma unroll
    for (int i = 0; i < 2; ++i) a[i] = *(const half8*)&As[w * 32 + i * 16 + m][q * 8];
#pragma unroll
    for (int j = 0; j < 8; ++j) b[j] = *(const half8*)&Bs[j * 16 + m][q * 8];
#pragma unroll
    for (int i = 0; i < 2; ++i)
#pragma unroll
      for (int j = 0; j < 8; ++j)
        acc[i][j] = __builtin_amdgcn_mfma_f32_16x16x32_f16(a[i], b[j], acc[i][j], 0, 0, 0);
  }
#pragma unroll
  for (int i = 0; i < 2; ++i)
#pragma unroll
    for (int j = 0; j < 8; ++j) {
      int col = bn * 128 + j * 16 + m;
      float bv = bias[col];
#pragma unroll
      for (int rr = 0; rr < 4; ++rr) {
        int row = bm * 128 + w * 32 + i * 16 + q * 4 + rr;  // row = b*512 + t
        size_t orow = (size_t)(row & 511) * 128 + (row >> 9);  // -> t*128 + b
        Cout[orow * 512 + col] = (_Float16)(acc[i][j][rr] + bv);
      }
    }
}

// ---------------- fused 2-layer recurrence, data-polling, encoded z ----------------
// 32 blocks x 512 thr. layer = blk>>4, ct = (blk>>3)&1, bt = blk&7.
// Block: batch rows [bt*16,+16), cols [ct*256,+256). U (and Wk for L1) register-resident.
__global__ __launch_bounds__(512, 2) void rnn_fused2(const float* __restrict__ Uw,
                                                     const float* __restrict__ Wkw,
                                                     const _Float16* __restrict__ xp,
                                                     _Float16* __restrict__ z0f,
                                                     _Float16* __restrict__ z1f,
                                                     const float* __restrict__ bc,
                                                     const float* __restrict__ sums) {
  __shared__ __align__(16) _Float16 az[2][8192];   // own-layer z_prev tiles (32 KB, L0 dbuf)
  __shared__ __align__(16) _Float16 azs[8192];     // L1: z0(s) shadow tile (16 KB)
  __shared__ __align__(16) _Float16 zo[8][16][40]; // per-wave output transpose (10 KB)
  const int tid = threadIdx.x;
  const int layer = blockIdx.x >> 4, ct = (blockIdx.x >> 3) & 1, bt = blockIdx.x & 7;
  const int lane = tid & 63, w = tid >> 6, m = lane & 15, q = lane >> 4;
  const int colbase = ct * 256 + w * 32;
  const int gSelf = ct * 512 + tid;        // granule this thread stores each step
  const int gPoll = (1 - ct) * 512 + tid;  // granule polled from the sibling block

  half8 ufr[2][16], wfr[2][16];
#pragma unroll
  for (int t = 0; t < 2; ++t) {
    const float* up = Uw + (size_t)(colbase + t * 16 + m) * 512 + q * 8;
    const float* wp = Wkw + (size_t)(colbase + t * 16 + m) * 512 + q * 8;
#pragma unroll
    for (int kk = 0; kk < 16; ++kk) {
      float4 f0 = *(const float4*)(up + kk * 32), f1 = *(const float4*)(up + kk * 32 + 4);
      ufr[t][kk] = (half8){(_Float16)f0.x, (_Float16)f0.y, (_Float16)f0.z, (_Float16)f0.w,
                           (_Float16)f1.x, (_Float16)f1.y, (_Float16)f1.z, (_Float16)f1.w};
      if (layer) {
        float4 g0 = *(const float4*)(wp + kk * 32), g1 = *(const float4*)(wp + kk * 32 + 4);
        wfr[t][kk] = (half8){(_Float16)g0.x, (_Float16)g0.y, (_Float16)g0.z, (_Float16)g0.w,
                             (_Float16)g1.x, (_Float16)g1.y, (_Float16)g1.z, (_Float16)g1.w};
      }
    }
  }
  const float corrU[2] = {-2.f * sums[colbase + m], -2.f * sums[colbase + 16 + m]};
  float cw[2] = {0.f, 0.f};
  if (layer) {
    cw[0] = -2.f * sums[512 + colbase + m] + bc[colbase + m];
    cw[1] = -2.f * sums[512 + colbase + 16 + m] + bc[colbase + 16 + m];
  }

  _Float16* zout = layer ? z1f : z0f;
  const char* selfB = (const char*)zout;  // self-layer tile base (poll source)

  if (layer) stage_azs(z0f + (size_t)bt * 8192, azs, tid);  // z0(0)

  H8 pvkeep;  // L1: own granule carried to next step's az fill

  for (int s = 0; s < 512; ++s) {
    float pin[8];
    if (layer == 0) {  // input term: issue early, consumed after MFMAs
      const _Float16* xb = xp + (size_t)s * 65536 + (size_t)(bt * 16) * 512;
#pragma unroll
      for (int t = 0; t < 2; ++t)
#pragma unroll
        for (int rr = 0; rr < 4; ++rr)
          pin[t * 4 + rr] = (float)xb[(size_t)(q * 4 + rr) * 512 + colbase + t * 16 + m];
    }

    floatx4 wk[2];
    wk[0] = (floatx4){0.f, 0.f, 0.f, 0.f};
    wk[1] = (floatx4){0.f, 0.f, 0.f, 0.f};
    _Float16* azcur = layer ? az[0] : az[s & 1];
    if (layer) {
      __syncthreads();  // (A) publish azs tail; az[0] WAR vs prev-iter U-MFMAs
      const char* srcB = (const char*)z1f + ((size_t)(s - 1) * 8 + bt) * 16384;
      u32x4 r16;
      if (s > 0) {
        *(half8*)&azcur[(size_t)gSelf * 8] = pvkeep.v;  // own half: from registers
        asm volatile("global_load_dwordx4 %0, %1, off sc0 sc1"
                     : "=&v"(r16) : "v"(srcB + (size_t)gPoll * 16) : "memory");
      }
#pragma unroll
      for (int kk = 0; kk < 16; ++kk) {  // Wk @ z0(s) (encoded; corrected via cw)
        half8 a = *(const half8*)&azs[((kk * 4 + q) * 16 + m) * 8];
        wk[0] = __builtin_amdgcn_mfma_f32_16x16x32_f16(a, wfr[0][kk], wk[0], 0, 0, 0);
        wk[1] = __builtin_amdgcn_mfma_f32_16x16x32_f16(a, wfr[1][kk], wk[1], 0, 0, 0);
      }
      if (s > 0) {
        asm volatile("s_waitcnt vmcnt(0)" ::: "memory");
        __builtin_amdgcn_sched_barrier(0);
        unsigned long long g[2];
        unsigned need = val16B(r16, g);
        retry16B(srcB + (size_t)gPoll * 16, g, need, 0);
        H8 t;
        t.u[0] = g[0];
        t.u[1] = g[1];
        *(half8*)&azcur[(size_t)gPoll * 8] = t.v;
      }
    } else {
      if (s > 0) {  // own half already in az[s&1] (written at prev iter end)
        const char* srcB = selfB + ((size_t)(s - 1) * 8 + bt) * 16384;
        u32x4 r16;
        asm volatile("global_load_dwordx4 %0, %1, off sc0 sc1"
                     : "=&v"(r16) : "v"(srcB + (size_t)gPoll * 16) : "memory");
        asm volatile("s_waitcnt vmcnt(0)" ::: "memory");
        __builtin_amdgcn_sched_barrier(0);
        unsigned long long g[2];
        unsigned need = val16B(r16, g);
        retry16B(srcB + (size_t)gPoll * 16, g, need, 0);
        H8 t;
        t.u[0] = g[0];
        t.u[1] = g[1];
        *(half8*)&azcur[(size_t)gPoll * 8] = t.v;
      }
    }
    __syncthreads();  // (A2) publish az

    floatx4 acc[2][2];
    acc[0][0] = (floatx4){0.f, 0.f, 0.f, 0.f};
    acc[0][1] = (floatx4){0.f, 0.f, 0.f, 0.f};
    acc[1][0] = (floatx4){0.f, 0.f, 0.f, 0.f};
    acc[1][1] = (floatx4){0.f, 0.f, 0.f, 0.f};
    if (s > 0) {
#pragma unroll
      for (int kk = 0; kk < 16; ++kk) {  // U @ z_prev (encoded; corrected via corrU)
        half8 a = *(const half8*)&azcur[((kk * 4 + q) * 16 + m) * 8];
        acc[0][kk & 1] = __builtin_amdgcn_mfma_f32_16x16x32_f16(a, ufr[0][kk], acc[0][kk & 1], 0, 0, 0);
        acc[1][kk & 1] = __builtin_amdgcn_mfma_f32_16x16x32_f16(a, ufr[1][kk], acc[1][kk & 1], 0, 0, 0);
      }
    }
#pragma unroll
    for (int t = 0; t < 2; ++t)
#pragma unroll
      for (int rr = 0; rr < 4; ++rr) {
        float x = layer ? (wk[t][rr] + cw[t]) : pin[t * 4 + rr];
        if (s > 0) x += acc[t][0][rr] + acc[t][1][rr] + corrU[t];
        // enc = tanh(x) + 2 = 3 - 2/(exp2(x*2/ln2)+1)
        float e = __builtin_exp2f(x * 2.885390081777927f);
        float enc = 3.f - 2.f * __builtin_amdgcn_rcpf(e + 1.f);
        zo[w][q * 4 + rr][t * 16 + m] = (_Float16)enc;
      }
    asm volatile("s_waitcnt lgkmcnt(0)" ::: "memory");  // wave-sync LDS w->r
    __builtin_amdgcn_sched_barrier(0);
    {
      H8 pv;
      pv.v = *(const half8*)&zo[w][m][q * 8];  // == granule gSelf = 512*ct + tid
      char* dstB = (char*)zout + (((size_t)s * 8 + bt) * 1024 + (size_t)gSelf) * 16;
      u32x4 pd;
      pd[0] = (unsigned)pv.u[0];
      pd[1] = (unsigned)(pv.u[0] >> 32);
      pd[2] = (unsigned)pv.u[1];
      pd[3] = (unsigned)(pv.u[1] >> 32);
      asm volatile("global_store_dwordx4 %0, %1, off sc0 sc1" :: "v"(dstB), "v"(pd) : "memory");
      if (layer == 0) {
        // own half for next step, direct to the other az buffer (dbuf -> safe:
        // readers of az[(s+1)&1] finished before this iter's A2)
        *(half8*)&az[(s + 1) & 1][(size_t)gSelf * 8] = pv.v;
      } else {
        pvkeep = pv;  // deferred past next iter's barrier A (az[0] WAR)
      }
    }
    if (layer && s < 511)  // shadow: stage z0(s+1) for next step's Wk part
      stage_azs(z0f + ((size_t)(s + 1) * 8 + bt) * 8192, azs, tid);
  }
}

// ---------------- y = z1 @ V^T + bco : z1 encoded in zfrag layout ----------------
__global__ __launch_bounds__(64) void out_gemm(const _Float16* __restrict__ z1,
                                               const _Float16* __restrict__ V16,
                                               const float* __restrict__ bco,
                                               float* __restrict__ out) {
  __shared__ __align__(16) _Float16 zt[16][520];
  __shared__ __align__(16) _Float16 vt[16][520];
  const int tid = threadIdx.x;
  const int m = tid & 15, q = tid >> 4;
  const size_t r0 = (size_t)blockIdx.x * 16;  // r = t*128 + b
  for (int idx = tid; idx < 1024; idx += 64) {
    int row = idx >> 6, ch = idx & 63;
    int r = (int)(r0 + row), t = r >> 7, b = r & 127;
    size_t off = (size_t)(t * 8 + (b >> 4)) * 8192 + (size_t)ch * 128 + (b & 15) * 8;
    *(half8*)&zt[row][ch * 8] = *(const half8*)&z1[off];
    *(half8*)&vt[row][ch * 8] = *(const half8*)&V16[(size_t)row * 512 + ch * 8];
  }
  __syncthreads();
  floatx4 acc = {0.f, 0.f, 0.f, 0.f};
#pragma unroll
  for (int kk = 0; kk < 16; ++kk) {
    half8 a = *(const half8*)&zt[m][kk * 32 + q * 8];
    half8 b = *(const half8*)&vt[m][kk * 32 + q * 8];
    acc = __builtin_amdgcn_mfma_f32_16x16x32_f16(a, b, acc, 0, 0, 0);
  }
  if (m < 9) {
#pragma unroll
    for (int rr = 0; rr < 4; ++rr) {
      size_t r = r0 + q * 4 + rr;
      size_t t = r >> 7, b = r & 127;
      out[(b * 512 + t) * 9 + m] = acc[rr] + bco[m];
    }
  }
}

extern "C" void kernel_launch(void* const* d_in, const int* in_sizes, int n_in,
                              void* d_out, int out_size, void* d_ws, size_t ws_size,
                              hipStream_t stream) {
  const float* emb = (const float*)d_in[0];  // [128][512][256]
  const float* Ww  = (const float*)d_in[1];  // [512][256]
  const float* Wb  = (const float*)d_in[2];  // [512]
  const float* Ukw = (const float*)d_in[3];  // [2][512][512] (only [0] used)
  const float* Ukb = (const float*)d_in[4];  // [2][512]      (only [0] used)
  const float* Wkw = (const float*)d_in[5];  // [1][512][512]
  const float* Wkb = (const float*)d_in[6];  // [1][512]
  const float* Vw  = (const float*)d_in[7];  // [9][512]
  const float* Vb  = (const float*)d_in[8];  // [9]
  float* out = (float*)d_out;                // [128][512][9] f32

  char* ws = (char*)d_ws;
  _Float16* xp   = (_Float16*)(ws + 0);          // [T][B][H] f16 t-major, 64 MB
  _Float16* z0f  = (_Float16*)(ws + 67108864);   // zfrag (encoded), 64 MB
  _Float16* z1f  = (_Float16*)(ws + 134217728);  // zfrag (encoded), 64 MB
  _Float16* V16  = (_Float16*)(ws + 201326592);  // 16 KB
  float* bxp     = (float*)(ws + 201342976);
  float* bc      = (float*)(ws + 201345024);
  float* sums    = (float*)(ws + 201347072);     // SU[512], SW[512], bco[16]

  hipLaunchKernelGGL(prep_small, dim3(32), dim3(256), 0, stream,
                     Vw, Vb, Wb, Ukb, Wkb, Ukw, Wkw, V16, bxp, bc, sums);
  hipLaunchKernelGGL(gemm_xp, dim3(512, 4), dim3(256), 0, stream, emb, Ww, xp, bxp);
  hipLaunchKernelGGL(rnn_fused2, dim3(32), dim3(512), 0, stream,
                     Ukw, Wkw, xp, z0f, z1f, bc, sums);
  hipLaunchKernelGGL(out_gemm, dim3(4096), dim3(64), 0, stream, z1f, V16, sums + 1024, out);
}

// Round 9
// 2714.771 us; speedup vs baseline: 1.3350x; 1.3350x over previous
//
#include <hip/hip_runtime.h>
#include <hip/hip_fp16.h>

typedef _Float16 half8 __attribute__((ext_vector_type(8)));
typedef float floatx4 __attribute__((ext_vector_type(4)));
typedef unsigned int u32x4 __attribute__((ext_vector_type(4)));

// B=128, T=512, E=256, H=512, OUT=9, L=2. Quirk: both layers use Uk_w[0]/Uk_b[0]
// -> L0 and L1 share the SAME U matrix (the basis of the merged design).
//
// zfrag layout (verified): 16B granules [t][bt][c16][b15]; granule g = c16*16+b15
// holds z[b = bt*16 + b15][h = c16*8 .. +8). Consumer lane (m,q) A-frag for
// K-block kk is granule (kk*4+q)*16 + m. Tile = 1024 granules = 16 KB.
// Thread tid's own produced granule = ct*256 + tid (verified identity).
//
// ENCODED STORAGE: z stored as enc = z + 2 (f16 in [1,3], bits 0x3C00..0x4200).
// Poison 0xAA and zeros fall outside -> an 8B word is valid iff its low f16 is
// in range. Each z address transitions poison->final exactly ONCE, so any
// stale/torn read returns poison (invalid), never valid-but-wrong.
//
// R9 = R8 resubmit (R8 failed on container infra, no kernel verdict) + one
// defensive change: s_sleep(1) between retry passes in the spin loops.
//
// MERGED-LAYER BLOCKS (volume attack; R3/R6 showed step time tracks poll
// volume; R7's split died on a 128-VGPR cap, not on the idea).
//  - 32 blocks x 256 thr (4 waves, launch_bounds(256,1) -> full reg budget,
//    same config that held R6's ufr+wfr union at VGPR_Count 228).
//  - Block (ct,bt) computes BOTH z0 and z1 for cols [ct*128,+128), rows
//    [bt*16,+16). ufr shared by both layers (the Uk_w[0] quirk).
//  - ONE z0 staging per step: z0(s) polled once -> Wk@z0(s) now, U@z0(s) next
//    step (az0 double buffer). R6 read each z0 tile twice.
//  - Own slice (256 granules) from registers/LDS; only 768 foreign granules
//    polled per tile: per-(bt,step) volume 192 KB -> 96 KB.
//  - z1 handoff pipelined across the step boundary (first-pass at step end,
//    validate next step); z0 poll RT hidden under U@z1 MFMAs. 2 barriers/step.
//  - Deadlock-free: store-own-slice ALWAYS precedes poll-foreign in program
//    order; 32 blocks co-resident (1/CU).

union H8 { half8 v; unsigned long long u[2]; };

__device__ __forceinline__ bool valid16(unsigned long long u) {
  return (unsigned)((unsigned)(u & 0xFFFFull) - 0x3C00u) <= 0x600u;  // f16 in [1.0, 3.0]
}

__device__ __forceinline__ unsigned val16B(u32x4 r, unsigned long long g[2]) {
  unsigned long long lo = ((unsigned long long)r[1] << 32) | r[0];
  unsigned long long hi = ((unsigned long long)r[3] << 32) | r[2];
  unsigned need = 0;
  if (valid16(lo)) g[0] = lo; else need |= 1u;
  if (valid16(hi)) g[1] = hi; else need |= 2u;
  return need;
}

__device__ __forceinline__ void retry16B(const char* addr, unsigned long long g[2],
                                         unsigned need) {
  while (need) {
    u32x4 r;
    asm volatile("global_load_dwordx4 %0, %1, off sc0 sc1" : "=&v"(r) : "v"(addr) : "memory");
    asm volatile("s_waitcnt vmcnt(0)" ::: "memory");
    __builtin_amdgcn_sched_barrier(0);
    unsigned long long lo = ((unsigned long long)r[1] << 32) | r[0];
    unsigned long long hi = ((unsigned long long)r[3] << 32) | r[2];
    if ((need & 1u) && valid16(lo)) { g[0] = lo; need &= ~1u; }
    if ((need & 2u) && valid16(hi)) { g[1] = hi; need &= ~2u; }
    if (need) __builtin_amdgcn_s_sleep(1);
  }
}

// ---------------- prep: V pad, fused biases, f16-rounded weight row-sums ----------------
__global__ void prep_small(const float* __restrict__ Vw, const float* __restrict__ Vb,
                           const float* __restrict__ Wb, const float* __restrict__ Ukb,
                           const float* __restrict__ Wkb, const float* __restrict__ Ukw,
                           const float* __restrict__ Wkw, _Float16* __restrict__ V16,
                           float* __restrict__ bxp, float* __restrict__ bc,
                           float* __restrict__ sums) {
  int i = blockIdx.x * blockDim.x + threadIdx.x;
  if (i < 16 * 512) {
    int o = i >> 9, k = i & 511;
    V16[i] = (_Float16)(o < 9 ? Vw[o * 512 + k] : 0.0f);
  }
  if (i < 512) {
    bxp[i] = Wb[i] + Ukb[i];   // layer-0 pre-activation bias (folded into xp)
    bc[i]  = Wkb[i] + Ukb[i];  // layer-1 pre-activation bias
  }
  if (i < 1024) {  // sums[0..511]=rowsum f16(U); [512..1023]=rowsum f16(Wk)
    const float* row = (i < 512) ? Ukw + (size_t)i * 512 : Wkw + (size_t)(i - 512) * 512;
    float s = 0.f;
    for (int k = 0; k < 512; k += 4) {
      float4 v = *(const float4*)(row + k);
      s += (float)(_Float16)v.x + (float)(_Float16)v.y + (float)(_Float16)v.z + (float)(_Float16)v.w;
    }
    sums[i] = s;
  } else if (i < 1040) {  // sums[1024..1039] = out bias: Vb - 2*rowsum f16(V)
    int o = i - 1024;
    float s = 0.f;
    if (o < 9) {
      const float* row = Vw + (size_t)o * 512;
      for (int k = 0; k < 512; k += 4) {
        float4 v = *(const float4*)(row + k);
        s += (float)(_Float16)v.x + (float)(_Float16)v.y + (float)(_Float16)v.z + (float)(_Float16)v.w;
      }
    }
    sums[i] = (o < 9 ? Vb[o] : 0.f) - 2.f * s;
  }
}

// ---------------- xp GEMM: xp[t][b][:] = emb[b][t][:] @ W^T + (Wb+Ukb0), f32 in, f16 out ----
__global__ __launch_bounds__(256) void gemm_xp(const float* __restrict__ Aptr,
                                               const float* __restrict__ Bptr,
                                               _Float16* __restrict__ Cout,
                                               const float* __restrict__ bias) {
  const int K = 256;
  __shared__ __align__(16) _Float16 As[128][40];
  __shared__ __align__(16) _Float16 Bs[128][40];
  const int tid = threadIdx.x;
  const int bm = blockIdx.x, bn = blockIdx.y;
  const int w = tid >> 6, lane = tid & 63;
  const int m = lane & 15, q = lane >> 4;

  floatx4 acc[2][8];
#pragma unroll
  for (int i = 0; i < 2; ++i)
#pragma unroll
    for (int j = 0; j < 8; ++j) acc[i][j] = (floatx4){0.f, 0.f, 0.f, 0.f};

  for (int kt = 0; kt < (K >> 5); ++kt) {
    const int k0 = kt << 5;
    __syncthreads();
#pragma unroll
    for (int it = 0; it < 2; ++it) {
      int idx = tid + it * 256;
      int row = idx >> 2, ch = idx & 3;
      size_t gA = (size_t)(bm * 128 + row) * K + (k0 + ch * 8);
      const float4* p = (const float4*)(Aptr + gA);
      float4 f0 = p[0], f1 = p[1];
      *(half8*)&As[row][ch * 8] =
          (half8){(_Float16)f0.x, (_Float16)f0.y, (_Float16)f0.z, (_Float16)f0.w,
                  (_Float16)f1.x, (_Float16)f1.y, (_Float16)f1.z, (_Float16)f1.w};
      size_t gB = (size_t)(bn * 128 + row) * K + (k0 + ch * 8);
      const float4* pb = (const float4*)(Bptr + gB);
      float4 g0 = pb[0], g1 = pb[1];
      *(half8*)&Bs[row][ch * 8] =
          (half8){(_Float16)g0.x, (_Float16)g0.y, (_Float16)g0.z, (_Float16)g0.w,
                  (_Float16)g1.x, (_Float16)g1.y, (_Float16)g1.z, (_Float16)g1.w};
    }
    __syncthreads();
    half8 a[2], b[8];
#pragma unroll
    for (int i = 0; i < 2; ++i) a[i] = *(const half8*)&As[w * 32 + i * 16 + m][q * 8];
#pragma unroll
    for (int j = 0; j < 8; ++j) b[j] = *(const half8*)&Bs[j * 16 + m][q * 8];
#pragma unroll
    for (int i = 0; i < 2; ++i)
#pragma unroll
      for (int j = 0; j < 8; ++j)
        acc[i][j] = __builtin_amdgcn_mfma_f32_16x16x32_f16(a[i], b[j], acc[i][j], 0, 0, 0);
  }
#pragma unroll
  for (int i = 0; i < 2; ++i)
#pragma unroll
    for (int j = 0; j < 8; ++j) {
      int col = bn * 128 + j * 16 + m;
      float bv = bias[col];
#pragma unroll
      for (int rr = 0; rr < 4; ++rr) {
        int row = bm * 128 + w * 32 + i * 16 + q * 4 + rr;  // row = b*512 + t
        size_t orow = (size_t)(row & 511) * 128 + (row >> 9);  // -> t*128 + b
        Cout[orow * 512 + col] = (_Float16)(acc[i][j][rr] + bv);
      }
    }
}

// ---------------- merged 2-layer recurrence, data-polling, encoded z ----------------
// 32 blocks x 256 thr. ct = blk>>3 (0..3), bt = blk&7 (same-XCD siblings).
// Block: batch rows [bt*16,+16), cols [ct*128,+128), BOTH layers.
__global__ __launch_bounds__(256, 1) void rnn_merged(const float* __restrict__ Uw,
                                                     const float* __restrict__ Wkw,
                                                     const _Float16* __restrict__ xp,
                                                     _Float16* __restrict__ z0f,
                                                     _Float16* __restrict__ z1f,
                                                     const float* __restrict__ bc,
                                                     const float* __restrict__ sums) {
  __shared__ __align__(16) _Float16 az0[2][8192];  // z0 tiles (32 KB, dbuf)
  __shared__ __align__(16) _Float16 az1[2][8192];  // z1 tiles (32 KB, dbuf)
  __shared__ __align__(16) _Float16 zo[4][16][40]; // per-wave transpose (5 KB)
  const int tid = threadIdx.x;
  const int ct = blockIdx.x >> 3, bt = blockIdx.x & 7;
  const int lane = tid & 63, w = tid >> 6, m = lane & 15, q = lane >> 4;
  const int colbase = ct * 128 + w * 32;
  const int gOwn = ct * 256 + tid;  // own produced granule (both layers)
  const int fc0 = (ct + 1) & 3, fc1 = (ct + 2) & 3, fc2 = (ct + 3) & 3;

  half8 ufr[2][16], wfr[2][16];
#pragma unroll
  for (int t = 0; t < 2; ++t) {
    const float* up = Uw + (size_t)(colbase + t * 16 + m) * 512 + q * 8;
    const float* wp = Wkw + (size_t)(colbase + t * 16 + m) * 512 + q * 8;
#pragma unroll
    for (int kk = 0; kk < 16; ++kk) {
      float4 f0 = *(const float4*)(up + kk * 32), f1 = *(const float4*)(up + kk * 32 + 4);
      ufr[t][kk] = (half8){(_Float16)f0.x, (_Float16)f0.y, (_Float16)f0.z, (_Float16)f0.w,
                           (_Float16)f1.x, (_Float16)f1.y, (_Float16)f1.z, (_Float16)f1.w};
      float4 g0 = *(const float4*)(wp + kk * 32), g1 = *(const float4*)(wp + kk * 32 + 4);
      wfr[t][kk] = (half8){(_Float16)g0.x, (_Float16)g0.y, (_Float16)g0.z, (_Float16)g0.w,
                           (_Float16)g1.x, (_Float16)g1.y, (_Float16)g1.z, (_Float16)g1.w};
    }
  }
  const float corrU[2] = {-2.f * sums[colbase + m], -2.f * sums[colbase + 16 + m]};
  const float cwv[2] = {-2.f * sums[512 + colbase + m] + bc[colbase + m],
                        -2.f * sums[512 + colbase + 16 + m] + bc[colbase + 16 + m]};

  u32x4 z1r[3];  // z1 foreign first-pass (issued at step end, validated next step)

  for (int s = 0; s < 512; ++s) {
    const int p = s & 1;  // az*[p] holds step s-1 data; az*[1-p] receives step s

    // ---- xp input term (issue early; off-chain) ----
    float pin[8];
    {
      const _Float16* xb = xp + (size_t)s * 65536 + (size_t)(bt * 16) * 512;
#pragma unroll
      for (int t = 0; t < 2; ++t)
#pragma unroll
        for (int rr = 0; rr < 4; ++rr)
          pin[t * 4 + rr] = (float)xb[(size_t)(q * 4 + rr) * 512 + colbase + t * 16 + m];
    }

    // ---- validate z1(s-1) foreign (loads issued at end of step s-1) ----
    if (s > 0) {
      const char* z1src = (const char*)z1f + ((size_t)(s - 1) * 8 + bt) * 16384;
      asm volatile("s_waitcnt vmcnt(0)" ::: "memory");
      __builtin_amdgcn_sched_barrier(0);
      const int fcs[3] = {fc0, fc1, fc2};
#pragma unroll
      for (int j = 0; j < 3; ++j) {
        unsigned long long g[2];
        unsigned need = val16B(z1r[j], g);
        retry16B(z1src + (size_t)(fcs[j] * 256 + tid) * 16, g, need);
        H8 t;
        t.u[0] = g[0];
        t.u[1] = g[1];
        *(half8*)&az1[p][(size_t)(fcs[j] * 256 + tid) * 8] = t.v;
      }
    }
    __syncthreads();  // B1: az1[p] complete (az0[p] complete via prev step's B2+writes)

    // ---- z0(s) = tanh(xp + U @ z0(s-1)) ----
    floatx4 a0[2][2];
    a0[0][0] = a0[0][1] = a0[1][0] = a0[1][1] = (floatx4){0.f, 0.f, 0.f, 0.f};
    if (s > 0) {
#pragma unroll
      for (int kk = 0; kk < 16; ++kk) {
        half8 a = *(const half8*)&az0[p][((kk * 4 + q) * 16 + m) * 8];
        a0[0][kk & 1] = __builtin_amdgcn_mfma_f32_16x16x32_f16(a, ufr[0][kk], a0[0][kk & 1], 0, 0, 0);
        a0[1][kk & 1] = __builtin_amdgcn_mfma_f32_16x16x32_f16(a, ufr[1][kk], a0[1][kk & 1], 0, 0, 0);
      }
    }
#pragma unroll
    for (int t = 0; t < 2; ++t)
#pragma unroll
      for (int rr = 0; rr < 4; ++rr) {
        float x = pin[t * 4 + rr];
        if (s > 0) x += a0[t][0][rr] + a0[t][1][rr] + corrU[t];
        float e = __builtin_exp2f(x * 2.885390081777927f);
        float enc = 3.f - 2.f * __builtin_amdgcn_rcpf(e + 1.f);  // tanh(x)+2
        zo[w][q * 4 + rr][t * 16 + m] = (_Float16)enc;
      }
    asm volatile("s_waitcnt lgkmcnt(0)" ::: "memory");
    __builtin_amdgcn_sched_barrier(0);
    u32x4 zr[3];
    {
      H8 pv;
      pv.v = *(const half8*)&zo[w][m][q * 8];  // granule gOwn
      char* d0 = (char*)z0f + (((size_t)s * 8 + bt) * 1024 + (size_t)gOwn) * 16;
      u32x4 pd;
      pd[0] = (unsigned)pv.u[0];
      pd[1] = (unsigned)(pv.u[0] >> 32);
      pd[2] = (unsigned)pv.u[1];
      pd[3] = (unsigned)(pv.u[1] >> 32);
      asm volatile("global_store_dwordx4 %0, %1, off sc0 sc1" :: "v"(d0), "v"(pd) : "memory");
      *(half8*)&az0[1 - p][(size_t)gOwn * 8] = pv.v;  // own slice: no poll
      // issue foreign z0(s) polls (validated after U@z1 below)
      const char* z0src = (const char*)z0f + ((size_t)s * 8 + bt) * 16384;
      asm volatile("global_load_dwordx4 %0, %1, off sc0 sc1"
                   : "=&v"(zr[0]) : "v"(z0src + (size_t)(fc0 * 256 + tid) * 16) : "memory");
      asm volatile("global_load_dwordx4 %0, %1, off sc0 sc1"
                   : "=&v"(zr[1]) : "v"(z0src + (size_t)(fc1 * 256 + tid) * 16) : "memory");
      asm volatile("global_load_dwordx4 %0, %1, off sc0 sc1"
                   : "=&v"(zr[2]) : "v"(z0src + (size_t)(fc2 * 256 + tid) * 16) : "memory");
    }

    // ---- U @ z1(s-1) (hides the z0 poll RT) ----
    floatx4 a1[2][2];
    a1[0][0] = a1[0][1] = a1[1][0] = a1[1][1] = (floatx4){0.f, 0.f, 0.f, 0.f};
    if (s > 0) {
#pragma unroll
      for (int kk = 0; kk < 16; ++kk) {
        half8 a = *(const half8*)&az1[p][((kk * 4 + q) * 16 + m) * 8];
        a1[0][kk & 1] = __builtin_amdgcn_mfma_f32_16x16x32_f16(a, ufr[0][kk], a1[0][kk & 1], 0, 0, 0);
        a1[1][kk & 1] = __builtin_amdgcn_mfma_f32_16x16x32_f16(a, ufr[1][kk], a1[1][kk & 1], 0, 0, 0);
      }
    }
    // ---- validate z0(s) foreign -> az0[1-p] ----
    {
      const char* z0src = (const char*)z0f + ((size_t)s * 8 + bt) * 16384;
      asm volatile("s_waitcnt vmcnt(0)" ::: "memory");
      __builtin_amdgcn_sched_barrier(0);
      const int fcs[3] = {fc0, fc1, fc2};
#pragma unroll
      for (int j = 0; j < 3; ++j) {
        unsigned long long g[2];
        unsigned need = val16B(zr[j], g);
        retry16B(z0src + (size_t)(fcs[j] * 256 + tid) * 16, g, need);
        H8 t;
        t.u[0] = g[0];
        t.u[1] = g[1];
        *(half8*)&az0[1 - p][(size_t)(fcs[j] * 256 + tid) * 8] = t.v;
      }
    }
    __syncthreads();  // B2: az0[1-p] (= z0(s)) complete

    // ---- z1(s) = tanh(Wk @ z0(s) + U @ z1(s-1) + bc) ----
#pragma unroll
    for (int kk = 0; kk < 16; ++kk) {
      half8 a = *(const half8*)&az0[1 - p][((kk * 4 + q) * 16 + m) * 8];
      a1[0][kk & 1] = __builtin_amdgcn_mfma_f32_16x16x32_f16(a, wfr[0][kk], a1[0][kk & 1], 0, 0, 0);
      a1[1][kk & 1] = __builtin_amdgcn_mfma_f32_16x16x32_f16(a, wfr[1][kk], a1[1][kk & 1], 0, 0, 0);
    }
#pragma unroll
    for (int t = 0; t < 2; ++t)
#pragma unroll
      for (int rr = 0; rr < 4; ++rr) {
        float x = a1[t][0][rr] + a1[t][1][rr] + cwv[t];
        if (s > 0) x += corrU[t];
        float e = __builtin_exp2f(x * 2.885390081777927f);
        float enc = 3.f - 2.f * __builtin_amdgcn_rcpf(e + 1.f);
        zo[w][q * 4 + rr][t * 16 + m] = (_Float16)enc;
      }
    asm volatile("s_waitcnt lgkmcnt(0)" ::: "memory");
    __builtin_amdgcn_sched_barrier(0);
    {
      H8 pv;
      pv.v = *(const half8*)&zo[w][m][q * 8];
      char* d1 = (char*)z1f + (((size_t)s * 8 + bt) * 1024 + (size_t)gOwn) * 16;
      u32x4 pd;
      pd[0] = (unsigned)pv.u[0];
      pd[1] = (unsigned)(pv.u[0] >> 32);
      pd[2] = (unsigned)pv.u[1];
      pd[3] = (unsigned)(pv.u[1] >> 32);
      asm volatile("global_store_dwordx4 %0, %1, off sc0 sc1" :: "v"(d1), "v"(pd) : "memory");
      *(half8*)&az1[1 - p][(size_t)gOwn * 8] = pv.v;  // own slice for next step
    }
    if (s < 511) {  // z1(s) foreign first-pass; validated at step s+1
      const char* nsrc = (const char*)z1f + ((size_t)s * 8 + bt) * 16384;
      asm volatile("global_load_dwordx4 %0, %1, off sc0 sc1"
                   : "=&v"(z1r[0]) : "v"(nsrc + (size_t)(fc0 * 256 + tid) * 16) : "memory");
      asm volatile("global_load_dwordx4 %0, %1, off sc0 sc1"
                   : "=&v"(z1r[1]) : "v"(nsrc + (size_t)(fc1 * 256 + tid) * 16) : "memory");
      asm volatile("global_load_dwordx4 %0, %1, off sc0 sc1"
                   : "=&v"(z1r[2]) : "v"(nsrc + (size_t)(fc2 * 256 + tid) * 16) : "memory");
    }
  }
}

// ---------------- y = z1 @ V^T + bco : z1 encoded in zfrag layout ----------------
__global__ __launch_bounds__(64) void out_gemm(const _Float16* __restrict__ z1,
                                               const _Float16* __restrict__ V16,
                                               const float* __restrict__ bco,
                                               float* __restrict__ out) {
  __shared__ __align__(16) _Float16 zt[16][520];
  __shared__ __align__(16) _Float16 vt[16][520];
  const int tid = threadIdx.x;
  const int m = tid & 15, q = tid >> 4;
  const size_t r0 = (size_t)blockIdx.x * 16;  // r = t*128 + b
  for (int idx = tid; idx < 1024; idx += 64) {
    int row = idx >> 6, ch = idx & 63;
    int r = (int)(r0 + row), t = r >> 7, b = r & 127;
    size_t off = (size_t)(t * 8 + (b >> 4)) * 8192 + (size_t)ch * 128 + (b & 15) * 8;
    *(half8*)&zt[row][ch * 8] = *(const half8*)&z1[off];
    *(half8*)&vt[row][ch * 8] = *(const half8*)&V16[(size_t)row * 512 + ch * 8];
  }
  __syncthreads();
  floatx4 acc = {0.f, 0.f, 0.f, 0.f};
#pragma unroll
  for (int kk = 0; kk < 16; ++kk) {
    half8 a = *(const half8*)&zt[m][kk * 32 + q * 8];
    half8 b = *(const half8*)&vt[m][kk * 32 + q * 8];
    acc = __builtin_amdgcn_mfma_f32_16x16x32_f16(a, b, acc, 0, 0, 0);
  }
  if (m < 9) {
#pragma unroll
    for (int rr = 0; rr < 4; ++rr) {
      size_t r = r0 + q * 4 + rr;
      size_t t = r >> 7, b = r & 127;
      out[(b * 512 + t) * 9 + m] = acc[rr] + bco[m];
    }
  }
}

extern "C" void kernel_launch(void* const* d_in, const int* in_sizes, int n_in,
                              void* d_out, int out_size, void* d_ws, size_t ws_size,
                              hipStream_t stream) {
  const float* emb = (const float*)d_in[0];  // [128][512][256]
  const float* Ww  = (const float*)d_in[1];  // [512][256]
  const float* Wb  = (const float*)d_in[2];  // [512]
  const float* Ukw = (const float*)d_in[3];  // [2][512][512] (only [0] used)
  const float* Ukb = (const float*)d_in[4];  // [2][512]      (only [0] used)
  const float* Wkw = (const float*)d_in[5];  // [1][512][512]
  const float* Wkb = (const float*)d_in[6];  // [1][512]
  const float* Vw  = (const float*)d_in[7];  // [9][512]
  const float* Vb  = (const float*)d_in[8];  // [9]
  float* out = (float*)d_out;                // [128][512][9] f32

  char* ws = (char*)d_ws;
  _Float16* xp   = (_Float16*)(ws + 0);          // [T][B][H] f16 t-major, 64 MB
  _Float16* z0f  = (_Float16*)(ws + 67108864);   // zfrag (encoded), 64 MB
  _Float16* z1f  = (_Float16*)(ws + 134217728);  // zfrag (encoded), 64 MB
  _Float16* V16  = (_Float16*)(ws + 201326592);  // 16 KB
  float* bxp     = (float*)(ws + 201342976);
  float* bc      = (float*)(ws + 201345024);
  float* sums    = (float*)(ws + 201347072);     // SU[512], SW[512], bco[16]

  hipLaunchKernelGGL(prep_small, dim3(32), dim3(256), 0, stream,
                     Vw, Vb, Wb, Ukb, Wkb, Ukw, Wkw, V16, bxp, bc, sums);
  hipLaunchKernelGGL(gemm_xp, dim3(512, 4), dim3(256), 0, stream, emb, Ww, xp, bxp);
  hipLaunchKernelGGL(rnn_merged, dim3(32), dim3(256), 0, stream,
                     Ukw, Wkw, xp, z0f, z1f, bc, sums);
  hipLaunchKernelGGL(out_gemm, dim3(4096), dim3(64), 0, stream, z1f, V16, sums + 1024, out);
}